// Round 12
// baseline (406.969 us; speedup 1.0000x reference)
//
#include <hip/hip_runtime.h>
#include <math.h>

#define B_ 32
#define F_ 128
#define H_ 256
#define N_ 2048
#define L_ 2
#define E_ 262144
#define NN_ 65536          // B_*N_
// DEG = E/(B*N) = 4

typedef __attribute__((ext_vector_type(8))) short short8;   // 8 bf16 = 4 VGPRs (MFMA A/B frag)
typedef __attribute__((ext_vector_type(4))) float f32x4;    // MFMA C/D frag

static __device__ __forceinline__ unsigned short f2bf(float f) {
  unsigned int u = __float_as_uint(f);
  u += 0x7FFF + ((u >> 16) & 1);      // round-to-nearest-even
  return (unsigned short)(u >> 16);
}
static __device__ __forceinline__ float bf2f(unsigned short u) {
  return __uint_as_float(((unsigned int)u) << 16);
}

// ---------------- small kernels ----------------

__global__ void h0_kernel(const float* __restrict__ x, const float* __restrict__ W_in,
                          const float* __restrict__ b_in, float* __restrict__ h0) {
  int b = blockIdx.x;
  int j = threadIdx.x;
  float acc = b_in[j];
#pragma unroll 8
  for (int k = 0; k < F_; ++k)
    acc += x[b * F_ + k] * W_in[k * H_ + j];
  h0[b * H_ + j] = acc;
}

// fused mean-distance + geometric MLP: one block per node n
__global__ void meand_g_kernel(const float* __restrict__ positions,
                               const float* __restrict__ Wg1, const float* __restrict__ bg1,
                               const float* __restrict__ Wg2, const float* __restrict__ bg2,
                               float* __restrict__ g) {
  __shared__ float red[256];
  __shared__ float hid[128];
  int n = blockIdx.x;
  int t = threadIdx.x;
  float px = positions[n * 3 + 0], py = positions[n * 3 + 1], pz = positions[n * 3 + 2];
  float s = 0.f;
  for (int j = t; j < N_; j += 256) {
    float dx = px - positions[j * 3 + 0];
    float dy = py - positions[j * 3 + 1];
    float dz = pz - positions[j * 3 + 2];
    s += sqrtf(dx * dx + dy * dy + dz * dz);
  }
  red[t] = s;
  __syncthreads();
  for (int off = 128; off > 0; off >>= 1) {
    if (t < off) red[t] += red[t + off];
    __syncthreads();
  }
  float md = red[0] / (float)(N_ - 1);
  if (t < 128) {
    float w = Wg1[t] + Wg1[128 + t] + Wg1[256 + t];
    hid[t] = fmaxf(md * w + bg1[t], 0.f);
  }
  __syncthreads();
  float acc = bg2[t];
#pragma unroll 8
  for (int k = 0; k < 128; ++k)
    acc += hid[k] * Wg2[k * H_ + t];
  g[n * H_ + t] = acc;
}

// hbf[b*N+n][:] = bf16(h0[b][:] + g[n][:])  — bf16-only node state
__global__ void hbfinit_kernel(const float* __restrict__ h0, const float* __restrict__ g,
                               unsigned short* __restrict__ hbf) {
  int idx = blockIdx.x * blockDim.x + threadIdx.x;  // NN*32, 8 ch each
  int row = idx >> 5;
  int c8 = (idx & 31) << 3;
  const float* hp = h0 + (row >> 11) * H_ + c8;
  const float* gp = g + (row & (N_ - 1)) * H_ + c8;
  const float4 a = *(const float4*)hp;
  const float4 a2 = *(const float4*)(hp + 4);
  const float4 b = *(const float4*)gp;
  const float4 b2 = *(const float4*)(gp + 4);
  short8 v;
  v[0] = (short)f2bf(a.x + b.x);  v[1] = (short)f2bf(a.y + b.y);
  v[2] = (short)f2bf(a.z + b.z);  v[3] = (short)f2bf(a.w + b.w);
  v[4] = (short)f2bf(a2.x + b2.x); v[5] = (short)f2bf(a2.y + b2.y);
  v[6] = (short)f2bf(a2.z + b2.z); v[7] = (short)f2bf(a2.w + b2.w);
  *(short8*)(hbf + (((size_t)row) << 8) + c8) = v;
}

// pos stride-4 (float4-aligned): pos4[n] = {p.x, p.y, p.z, 0}
__global__ void posinit_kernel(const float* __restrict__ positions, float* __restrict__ pos4) {
  int n = blockIdx.x * blockDim.x + threadIdx.x;   // 0..NN-1
  int src = (n & (N_ - 1)) * 3;
  float4 v;
  v.x = positions[src + 0];
  v.y = positions[src + 1];
  v.z = positions[src + 2];
  v.w = 0.f;
  *(float4*)(pos4 + ((size_t)n << 2)) = v;
}

// ---------------- CSR build (counting sort of edges by dst) ----------------

__global__ void deg_kernel(const int* __restrict__ ei, int* __restrict__ deg) {
  int e = blockIdx.x * 256 + threadIdx.x;
  atomicAdd(&deg[ei[E_ + e]], 1);
}

__global__ void scan1_kernel(const int* __restrict__ deg, int* __restrict__ bsum) {
  __shared__ int red[256];
  int t = threadIdx.x;
  red[t] = deg[blockIdx.x * 256 + t];
  __syncthreads();
  for (int off = 128; off > 0; off >>= 1) {
    if (t < off) red[t] += red[t + off];
    __syncthreads();
  }
  if (t == 0) bsum[blockIdx.x] = red[0];
}

__global__ void scan2_kernel(int* __restrict__ bsum) {
  __shared__ int s[256];
  int t = threadIdx.x;
  s[t] = bsum[t];
  __syncthreads();
  for (int off = 1; off < 256; off <<= 1) {
    int v = (t >= off) ? s[t - off] : 0;
    __syncthreads();
    s[t] += v;
    __syncthreads();
  }
  bsum[t] = (t == 0) ? 0 : s[t - 1];
}

// writes BOTH cur and rowptr (no d2d copy)
__global__ void scan3_kernel(const int* __restrict__ deg, const int* __restrict__ bsum,
                             int* __restrict__ cur, int* __restrict__ rowptr) {
  __shared__ int s[256];
  int t = threadIdx.x;
  int i = blockIdx.x * 256 + t;
  s[t] = deg[i];
  __syncthreads();
  for (int off = 1; off < 256; off <<= 1) {
    int v = (t >= off) ? s[t - off] : 0;
    __syncthreads();
    s[t] += v;
    __syncthreads();
  }
  int excl = (t == 0) ? 0 : s[t - 1];
  int v = bsum[blockIdx.x] + excl;
  cur[i] = v;
  rowptr[i] = v;
}

__global__ void scatter_kernel(const int* __restrict__ ei, int* __restrict__ cur,
                               int* __restrict__ src_s) {
  int e = blockIdx.x * 256 + threadIdx.x;
  int s = ei[e], d = ei[E_ + e];
  int p = atomicAdd(&cur[d], 1);
  src_s[p] = s;
}

// ---------------- weight conversion (FRAGMENT-ORDER layout), single kernel ----------------
__global__ void wconv_all(const float* __restrict__ Wm, const float* __restrict__ Wu,
                          unsigned short* __restrict__ Wt1, unsigned short* __restrict__ Wut) {
  int idx = blockIdx.x * 256 + threadIdx.x;    // 0..65535
  int sel = idx >> 14;                          // 0,1: Wm l0,l1 ; 2,3: Wu l0,l1
  int rem = idx & 16383;
  if (sel < 2) {
    const float* W = Wm + (size_t)sel * 513 * H_;
    unsigned short* dst = Wt1 + (size_t)sel * 131072 + ((size_t)rem << 3);
    int g = rem >> 13;
    int r2 = rem & 8191;
    int kc = r2 >> 11, w = (r2 >> 9) & 3, ks = (r2 >> 8) & 1, ni = (r2 >> 6) & 3, lane = r2 & 63;
    int r = lane & 15, q = lane >> 4;
    int n  = (w << 6) + (ni << 4) + r;
    int kb = (g << 8) + (kc << 6) + (ks << 5) + (q << 3);
#pragma unroll
    for (int j = 0; j < 8; ++j)
      dst[j] = f2bf(W[(size_t)(kb + j) * H_ + n]);
  } else {
    const float* W = Wu + (size_t)(sel - 2) * 512 * H_;
    unsigned short* dst = Wut + (size_t)(sel - 2) * 131072 + ((size_t)rem << 3);
    int kc = rem >> 11, w = (rem >> 9) & 3, ks = (rem >> 8) & 1, ni = (rem >> 6) & 3, lane = rem & 63;
    int r = lane & 15, q = lane >> 4;
    int n  = (w << 6) + (ni << 4) + r;
    int kb = (kc << 6) + (ks << 5) + (q << 3);
#pragma unroll
    for (int j = 0; j < 8; ++j)
      dst[j] = f2bf(W[(size_t)(kb + j) * H_ + n]);
  }
}

// ---------------- GEMM1 single-pass (round-10 proven, unchanged) ----------------
__launch_bounds__(256)
__global__ void gemm1_mfma(const unsigned short* __restrict__ hbf,
                           const unsigned short* __restrict__ Wt,
                           const float* __restrict__ bm,
                           unsigned short* __restrict__ X, unsigned short* __restrict__ Zb) {
  __shared__ __align__(16) unsigned short sA[64 * 264];   // 33 KB, full K

  const int t = threadIdx.x;
  const int m0 = blockIdx.x << 6;
  const int w = t >> 6;
  const int lane = t & 63;
  const int q = lane >> 4;
  const int r = lane & 15;
  const int eA = t >> 2;
  const int jA = t & 3;

#pragma unroll
  for (int kc = 0; kc < 4; ++kc) {
    const unsigned short* src = hbf + (((size_t)(m0 + eA)) << 8) + (kc << 6) + (jA << 4);
    unsigned short* dstp = sA + eA * 264 + (kc << 6) + (jA << 4);
    *(short8*)(dstp) = *(const short8*)(src);
    *(short8*)(dstp + 8) = *(const short8*)(src + 8);
  }
  __syncthreads();

  for (int g = 0; g < 2; ++g) {
    f32x4 acc[4][4];
#pragma unroll
    for (int mi = 0; mi < 4; ++mi)
#pragma unroll
      for (int ni = 0; ni < 4; ++ni)
        acc[mi][ni] = (f32x4){0.f, 0.f, 0.f, 0.f};

#pragma unroll
    for (int kc = 0; kc < 4; ++kc) {
#pragma unroll
      for (int ks = 0; ks < 2; ++ks) {
        const int ko = (kc << 6) + (ks << 5) + (q << 3);
        short8 af[4], bfr[4];
#pragma unroll
        for (int mi = 0; mi < 4; ++mi)
          af[mi] = *(const short8*)(sA + (mi * 16 + r) * 264 + ko);
        const size_t wb = ((size_t)((((((g << 2) + kc) << 2) + w) << 1) + ks)) << 11;
#pragma unroll
        for (int ni = 0; ni < 4; ++ni)
          bfr[ni] = *(const short8*)(Wt + wb + (((ni << 6) + lane) << 3));
#pragma unroll
        for (int mi = 0; mi < 4; ++mi)
#pragma unroll
          for (int ni = 0; ni < 4; ++ni)
            acc[mi][ni] = __builtin_amdgcn_mfma_f32_16x16x32_bf16(af[mi], bfr[ni], acc[mi][ni], 0, 0, 0);
      }
    }

#pragma unroll
    for (int ni = 0; ni < 4; ++ni) {
      int n = (w << 6) + ni * 16 + r;
      float bmn = bm[n];
#pragma unroll
      for (int mi = 0; mi < 4; ++mi)
#pragma unroll
        for (int reg = 0; reg < 4; ++reg) {
          size_t idx = (((size_t)(m0 + mi * 16 + q * 4 + reg)) << 8) + n;
          float v = acc[mi][ni][reg];
          if (g == 0) X[idx]  = f2bf(v);
          else        Zb[idx] = f2bf(v + bmn);
        }
    }
  }
}

// ---------------- edge kernel: stride-4 pos, UNROLL-4 independent chains ----------------
__launch_bounds__(256)
__global__ void edge_kernel(const unsigned short* __restrict__ X,
                            const unsigned short* __restrict__ Zb,
                            const float* __restrict__ pos_c,   // stride-4
                            const int* __restrict__ rowptr, const int* __restrict__ src_s,
                            const float* __restrict__ wl, const float* __restrict__ wp,
                            unsigned short* __restrict__ aggb, float* __restrict__ pos_o) {
  const int gid = blockIdx.x * 256 + threadIdx.x;
  const int wave = gid >> 6;
  const int lane = threadIdx.x & 63;

  const float4 wlv = *(const float4*)(wl + (lane << 2));
  const float4 wpv = *(const float4*)(wp + (lane << 2));

#pragma unroll
  for (int ni = 0; ni < 4; ++ni) {
    const int n = (wave << 2) + ni;
    const int e0 = rowptr[n];
    const int e1 = (n == NN_ - 1) ? E_ : rowptr[n + 1];
    const ushort4 zv = *(const ushort4*)(Zb + (((size_t)n) << 8) + (lane << 2));
    const float z0 = bf2f(zv.x), z1 = bf2f(zv.y), z2 = bf2f(zv.z), z3 = bf2f(zv.w);
    const float4 pn = *(const float4*)(pos_c + ((size_t)n << 2));
    float a0 = 0.f, a1 = 0.f, a2 = 0.f, a3 = 0.f;
    float pdx = 0.f, pdy = 0.f, pdz = 0.f;     // per-lane partials (cp unreduced)

    int e = e0;
    for (; e + 4 <= e1; e += 4) {
      // issue all index loads, then all pos loads, then all X loads (4 chains in flight)
      const int s0 = src_s[e];
      const int s1 = src_s[e + 1];
      const int s2 = src_s[e + 2];
      const int s3 = src_s[e + 3];
      const float4 q0 = *(const float4*)(pos_c + ((size_t)s0 << 2));
      const float4 q1 = *(const float4*)(pos_c + ((size_t)s1 << 2));
      const float4 q2 = *(const float4*)(pos_c + ((size_t)s2 << 2));
      const float4 q3 = *(const float4*)(pos_c + ((size_t)s3 << 2));
      const ushort4 xv0 = *(const ushort4*)(X + (((size_t)s0) << 8) + (lane << 2));
      const ushort4 xv1 = *(const ushort4*)(X + (((size_t)s1) << 8) + (lane << 2));
      const ushort4 xv2 = *(const ushort4*)(X + (((size_t)s2) << 8) + (lane << 2));
      const ushort4 xv3 = *(const ushort4*)(X + (((size_t)s3) << 8) + (lane << 2));
#define EDGE_BODY(qv, xv)                                                     \
      {                                                                       \
        const float dx = pn.x - qv.x, dy = pn.y - qv.y, dz = pn.z - qv.z;     \
        const float d = sqrtf(dx * dx + dy * dy + dz * dz + 1e-12f);          \
        const float v0 = fmaxf(bf2f(xv.x) + z0 + d * wlv.x, 0.f);             \
        const float v1 = fmaxf(bf2f(xv.y) + z1 + d * wlv.y, 0.f);             \
        const float v2 = fmaxf(bf2f(xv.z) + z2 + d * wlv.z, 0.f);             \
        const float v3 = fmaxf(bf2f(xv.w) + z3 + d * wlv.w, 0.f);             \
        a0 += v0; a1 += v1; a2 += v2; a3 += v3;                               \
        const float cp = v0 * wpv.x + v1 * wpv.y + v2 * wpv.z + v3 * wpv.w;   \
        pdx += dx * cp; pdy += dy * cp; pdz += dz * cp;                       \
      }
      EDGE_BODY(q0, xv0)
      EDGE_BODY(q1, xv1)
      EDGE_BODY(q2, xv2)
      EDGE_BODY(q3, xv3)
    }
    for (; e < e1; ++e) {
      const int s = src_s[e];
      const float4 q = *(const float4*)(pos_c + ((size_t)s << 2));
      const ushort4 xv = *(const ushort4*)(X + (((size_t)s) << 8) + (lane << 2));
      EDGE_BODY(q, xv)
    }
#undef EDGE_BODY

    ushort4 av;
    av.x = f2bf(a0); av.y = f2bf(a1); av.z = f2bf(a2); av.w = f2bf(a3);
    *(ushort4*)(aggb + (((size_t)n) << 8) + (lane << 2)) = av;
#pragma unroll
    for (int m = 1; m < 64; m <<= 1) {
      pdx += __shfl_xor(pdx, m, 64);
      pdy += __shfl_xor(pdy, m, 64);
      pdz += __shfl_xor(pdz, m, 64);
    }
    if (lane == 0) {
      float4 po;
      po.x = pn.x + pdx * 0.25f;
      po.y = pn.y + pdy * 0.25f;
      po.z = pn.z + pdz * 0.25f;
      po.w = 0.f;
      *(float4*)(pos_o + ((size_t)n << 2)) = po;
    }
  }
}

// ---------------- GEMM2 (non-final layers, round-9 proven, unchanged) ----------------
__launch_bounds__(256)
__global__ void upd2_mfma(unsigned short* __restrict__ hbf,
                          const unsigned short* __restrict__ aggb,
                          const unsigned short* __restrict__ Wt,
                          const float* __restrict__ bu) {
  __shared__ __align__(16) unsigned short sA[64 * 72];   // 9 KB

  const int t = threadIdx.x;
  const int m0 = blockIdx.x << 6;
  const int w = t >> 6;
  const int lane = t & 63;
  const int q = lane >> 4;
  const int r = lane & 15;
  const int eA = t >> 2;
  const int jA = t & 3;

  f32x4 acc[4][4];
#pragma unroll
  for (int mi = 0; mi < 4; ++mi)
#pragma unroll
    for (int ni = 0; ni < 4; ++ni)
      acc[mi][ni] = (f32x4){0.f, 0.f, 0.f, 0.f};

  for (int kc = 0; kc < 8; ++kc) {
    __syncthreads();
    {
      const unsigned short* base = (kc < 4) ? hbf : aggb;
      const unsigned short* src = base + (((size_t)(m0 + eA)) << 8) + ((kc & 3) << 6) + (jA << 4);
      unsigned short* dstp = sA + eA * 72 + (jA << 4);
      *(short8*)(dstp) = *(const short8*)(src);
      *(short8*)(dstp + 8) = *(const short8*)(src + 8);
    }
    __syncthreads();
#pragma unroll
    for (int ks = 0; ks < 2; ++ks) {
      const int ko = (ks << 5) + (q << 3);
      short8 af[4], bfr[4];
#pragma unroll
      for (int mi = 0; mi < 4; ++mi)
        af[mi] = *(const short8*)(sA + (mi * 16 + r) * 72 + ko);
      const size_t wb = ((size_t)((((kc << 2) + w) << 1) + ks)) << 11;
#pragma unroll
      for (int ni = 0; ni < 4; ++ni)
        bfr[ni] = *(const short8*)(Wt + wb + (((ni << 6) + lane) << 3));
#pragma unroll
      for (int mi = 0; mi < 4; ++mi)
#pragma unroll
        for (int ni = 0; ni < 4; ++ni)
          acc[mi][ni] = __builtin_amdgcn_mfma_f32_16x16x32_bf16(af[mi], bfr[ni], acc[mi][ni], 0, 0, 0);
    }
  }
  __syncthreads();

#pragma unroll
  for (int ni = 0; ni < 4; ++ni) {
    int n = (w << 6) + ni * 16 + r;
    float buv = bu[n];
#pragma unroll
    for (int mi = 0; mi < 4; ++mi)
#pragma unroll
      for (int reg = 0; reg < 4; ++reg) {
        size_t idx = (((size_t)(m0 + mi * 16 + q * 4 + reg)) << 8) + n;
        float v = bf2f(hbf[idx]) + fmaxf(acc[mi][ni][reg] + buv, 0.f);
        hbf[idx] = f2bf(v);
      }
  }
}

// ---------------- GEMM2 final layer with fused W_out projection (round-10 proven) ----------------
__launch_bounds__(256)
__global__ void upd2_out(const unsigned short* __restrict__ hbf,
                         const unsigned short* __restrict__ aggb,
                         const unsigned short* __restrict__ Wt,
                         const float* __restrict__ bu,
                         const float* __restrict__ Wout, const float* __restrict__ bout,
                         float* __restrict__ out) {
  __shared__ __align__(16) unsigned short sA[64 * 72];   // 9 KB
  __shared__ float sRed[4][64];

  const int t = threadIdx.x;
  const int m0 = blockIdx.x << 6;
  const int w = t >> 6;
  const int lane = t & 63;
  const int q = lane >> 4;
  const int r = lane & 15;
  const int eA = t >> 2;
  const int jA = t & 3;

  f32x4 acc[4][4];
#pragma unroll
  for (int mi = 0; mi < 4; ++mi)
#pragma unroll
    for (int ni = 0; ni < 4; ++ni)
      acc[mi][ni] = (f32x4){0.f, 0.f, 0.f, 0.f};

  for (int kc = 0; kc < 8; ++kc) {
    __syncthreads();
    {
      const unsigned short* base = (kc < 4) ? hbf : aggb;
      const unsigned short* src = base + (((size_t)(m0 + eA)) << 8) + ((kc & 3) << 6) + (jA << 4);
      unsigned short* dstp = sA + eA * 72 + (jA << 4);
      *(short8*)(dstp) = *(const short8*)(src);
      *(short8*)(dstp + 8) = *(const short8*)(src + 8);
    }
    __syncthreads();
#pragma unroll
    for (int ks = 0; ks < 2; ++ks) {
      const int ko = (ks << 5) + (q << 3);
      short8 af[4], bfr[4];
#pragma unroll
      for (int mi = 0; mi < 4; ++mi)
        af[mi] = *(const short8*)(sA + (mi * 16 + r) * 72 + ko);
      const size_t wb = ((size_t)((((kc << 2) + w) << 1) + ks)) << 11;
#pragma unroll
      for (int ni = 0; ni < 4; ++ni)
        bfr[ni] = *(const short8*)(Wt + wb + (((ni << 6) + lane) << 3));
#pragma unroll
      for (int mi = 0; mi < 4; ++mi)
#pragma unroll
        for (int ni = 0; ni < 4; ++ni)
          acc[mi][ni] = __builtin_amdgcn_mfma_f32_16x16x32_bf16(af[mi], bfr[ni], acc[mi][ni], 0, 0, 0);
    }
  }
  __syncthreads();

  float dotp[4][4];
#pragma unroll
  for (int mi = 0; mi < 4; ++mi)
#pragma unroll
    for (int reg = 0; reg < 4; ++reg)
      dotp[mi][reg] = 0.f;

#pragma unroll
  for (int ni = 0; ni < 4; ++ni) {
    int n = (w << 6) + ni * 16 + r;
    float buv = bu[n];
    float won = Wout[n];
#pragma unroll
    for (int mi = 0; mi < 4; ++mi)
#pragma unroll
      for (int reg = 0; reg < 4; ++reg) {
        size_t idx = (((size_t)(m0 + mi * 16 + q * 4 + reg)) << 8) + n;
        float v = bf2f(hbf[idx]) + fmaxf(acc[mi][ni][reg] + buv, 0.f);
        dotp[mi][reg] += v * won;
      }
  }
#pragma unroll
  for (int mask = 1; mask < 16; mask <<= 1)
#pragma unroll
    for (int mi = 0; mi < 4; ++mi)
#pragma unroll
      for (int reg = 0; reg < 4; ++reg)
        dotp[mi][reg] += __shfl_xor(dotp[mi][reg], mask, 64);
  if (r == 0) {
#pragma unroll
    for (int mi = 0; mi < 4; ++mi)
#pragma unroll
      for (int reg = 0; reg < 4; ++reg)
        sRed[w][mi * 16 + q * 4 + reg] = dotp[mi][reg];
  }
  __syncthreads();
  if (t < 64)
    out[m0 + t] = sRed[0][t] + sRed[1][t] + sRed[2][t] + sRed[3][t] + bout[0];
}

// ---------------- launcher ----------------

extern "C" void kernel_launch(void* const* d_in, const int* in_sizes, int n_in,
                              void* d_out, int out_size, void* d_ws, size_t ws_size,
                              hipStream_t stream) {
  const float* x         = (const float*)d_in[0];
  const float* positions = (const float*)d_in[1];
  const float* W_in      = (const float*)d_in[2];
  const float* b_in      = (const float*)d_in[3];
  const float* Wg1       = (const float*)d_in[4];
  const float* bg1       = (const float*)d_in[5];
  const float* Wg2       = (const float*)d_in[6];
  const float* bg2       = (const float*)d_in[7];
  const float* Wm        = (const float*)d_in[8];
  const float* bm        = (const float*)d_in[9];
  const float* Wu        = (const float*)d_in[10];
  const float* bu        = (const float*)d_in[11];
  const float* Wp        = (const float*)d_in[12];
  const float* W_out     = (const float*)d_in[13];
  const float* b_out     = (const float*)d_in[14];
  const int*   ei        = (const int*)d_in[15];
  float* out = (float*)d_out;

  // workspace layout — sequential, non-overlapping (pos stride-4: 1 MB each)
  char* ws = (char*)d_ws;
  unsigned short* hbf   = (unsigned short*)(ws);                 //   0       +32 MB
  unsigned short* X     = (unsigned short*)(ws +  33554432UL);   //  32 MB    +32 MB
  unsigned short* Zb    = (unsigned short*)(ws +  67108864UL);   //  64 MB    +32 MB
  unsigned short* aggb  = (unsigned short*)(ws + 100663296UL);   //  96 MB    +32 MB
  float*          posA  = (float*)(ws + 134217728UL);            // +1 MB (stride-4)
  float*          posB  = (float*)(ws + 135266304UL);            // +1 MB (stride-4)
  float*          g     = (float*)(ws + 136314880UL);            // +2 MB
  float*          h0    = (float*)(ws + 138412032UL);            // +32 KB
  unsigned short* Wt1   = (unsigned short*)(ws + 138444800UL);   // +512 KB (2 layers, frag-order)
  unsigned short* Wut   = (unsigned short*)(ws + 138969088UL);   // +512 KB (2 layers, frag-order)
  int*            deg   = (int*)(ws + 139493376UL);              // +256 KB
  int*            cur   = (int*)(ws + 139755520UL);              // +256 KB
  int*            bsum  = (int*)(ws + 140017664UL);              // +1 KB
  int*            rowptr= (int*)(ws + 140018688UL);              // +256 KB -> ends 140280832
  int*            src_s = (int*)(ws + 140280832UL);              // +1 MB   -> ends 141329408

  // ---- CSR (counting sort by dst) ----
  hipMemsetAsync(deg, 0, (size_t)NN_ * sizeof(int), stream);
  deg_kernel<<<E_ / 256, 256, 0, stream>>>(ei, deg);
  scan1_kernel<<<256, 256, 0, stream>>>(deg, bsum);
  scan2_kernel<<<1, 256, 0, stream>>>(bsum);
  scan3_kernel<<<256, 256, 0, stream>>>(deg, bsum, cur, rowptr);
  scatter_kernel<<<E_ / 256, 256, 0, stream>>>(ei, cur, src_s);

  // ---- weight conversion (frag-order, one kernel) ----
  wconv_all<<<256, 256, 0, stream>>>(Wm, Wu, Wt1, Wut);

  // ---- node/pos init ----
  h0_kernel<<<B_, 256, 0, stream>>>(x, W_in, b_in, h0);
  meand_g_kernel<<<N_, 256, 0, stream>>>(positions, Wg1, bg1, Wg2, bg2, g);
  hbfinit_kernel<<<NN_ * 32 / 256, 256, 0, stream>>>(h0, g, hbf);
  posinit_kernel<<<NN_ / 256, 256, 0, stream>>>(positions, posA);

  float* pos_cur = posA;
  float* pos_nxt = posB;
  for (int l = 0; l < L_; ++l) {
    gemm1_mfma<<<NN_ / 64, 256, 0, stream>>>(hbf, Wt1 + (size_t)l * 131072,
                                             bm + (size_t)l * H_, X, Zb);
    edge_kernel<<<NN_ / 16, 256, 0, stream>>>(X, Zb, pos_cur, rowptr, src_s,
                                              Wm + (size_t)l * 513 * H_ + 512 * H_,
                                              Wp + (size_t)l * H_, aggb, pos_nxt);
    if (l < L_ - 1) {
      upd2_mfma<<<NN_ / 64, 256, 0, stream>>>(hbf, aggb, Wut + (size_t)l * 131072,
                                              bu + (size_t)l * H_);
    } else {
      upd2_out<<<NN_ / 64, 256, 0, stream>>>(hbf, aggb, Wut + (size_t)l * 131072,
                                             bu + (size_t)l * H_, W_out, b_out, out);
    }
    float* tmp = pos_cur; pos_cur = pos_nxt; pos_nxt = tmp;
  }
}

// Round 13
// 376.875 us; speedup vs baseline: 1.0799x; 1.0799x over previous
//
#include <hip/hip_runtime.h>
#include <math.h>

#define B_ 32
#define F_ 128
#define H_ 256
#define N_ 2048
#define L_ 2
#define E_ 262144
#define NN_ 65536          // B_*N_
// DEG = E/(B*N) = 4

typedef __attribute__((ext_vector_type(8))) short short8;   // 8 bf16 = 4 VGPRs (MFMA A/B frag)
typedef __attribute__((ext_vector_type(4))) float f32x4;    // MFMA C/D frag

static __device__ __forceinline__ unsigned short f2bf(float f) {
  unsigned int u = __float_as_uint(f);
  u += 0x7FFF + ((u >> 16) & 1);      // round-to-nearest-even
  return (unsigned short)(u >> 16);
}
static __device__ __forceinline__ float bf2f(unsigned short u) {
  return __uint_as_float(((unsigned int)u) << 16);
}

// ---------------- small kernels ----------------

__global__ void h0_kernel(const float* __restrict__ x, const float* __restrict__ W_in,
                          const float* __restrict__ b_in, float* __restrict__ h0) {
  int b = blockIdx.x;
  int j = threadIdx.x;
  float acc = b_in[j];
#pragma unroll 8
  for (int k = 0; k < F_; ++k)
    acc += x[b * F_ + k] * W_in[k * H_ + j];
  h0[b * H_ + j] = acc;
}

// fused mean-distance + geometric MLP: one block per node n
__global__ void meand_g_kernel(const float* __restrict__ positions,
                               const float* __restrict__ Wg1, const float* __restrict__ bg1,
                               const float* __restrict__ Wg2, const float* __restrict__ bg2,
                               float* __restrict__ g) {
  __shared__ float red[256];
  __shared__ float hid[128];
  int n = blockIdx.x;
  int t = threadIdx.x;
  float px = positions[n * 3 + 0], py = positions[n * 3 + 1], pz = positions[n * 3 + 2];
  float s = 0.f;
  for (int j = t; j < N_; j += 256) {
    float dx = px - positions[j * 3 + 0];
    float dy = py - positions[j * 3 + 1];
    float dz = pz - positions[j * 3 + 2];
    s += sqrtf(dx * dx + dy * dy + dz * dz);
  }
  red[t] = s;
  __syncthreads();
  for (int off = 128; off > 0; off >>= 1) {
    if (t < off) red[t] += red[t + off];
    __syncthreads();
  }
  float md = red[0] / (float)(N_ - 1);
  if (t < 128) {
    float w = Wg1[t] + Wg1[128 + t] + Wg1[256 + t];
    hid[t] = fmaxf(md * w + bg1[t], 0.f);
  }
  __syncthreads();
  float acc = bg2[t];
#pragma unroll 8
  for (int k = 0; k < 128; ++k)
    acc += hid[k] * Wg2[k * H_ + t];
  g[n * H_ + t] = acc;
}

// hbf[b*N+n][:] = bf16(h0[b][:] + g[n][:])  — bf16-only node state
__global__ void hbfinit_kernel(const float* __restrict__ h0, const float* __restrict__ g,
                               unsigned short* __restrict__ hbf) {
  int idx = blockIdx.x * blockDim.x + threadIdx.x;  // NN*32, 8 ch each
  int row = idx >> 5;
  int c8 = (idx & 31) << 3;
  const float* hp = h0 + (row >> 11) * H_ + c8;
  const float* gp = g + (row & (N_ - 1)) * H_ + c8;
  const float4 a = *(const float4*)hp;
  const float4 a2 = *(const float4*)(hp + 4);
  const float4 b = *(const float4*)gp;
  const float4 b2 = *(const float4*)(gp + 4);
  short8 v;
  v[0] = (short)f2bf(a.x + b.x);  v[1] = (short)f2bf(a.y + b.y);
  v[2] = (short)f2bf(a.z + b.z);  v[3] = (short)f2bf(a.w + b.w);
  v[4] = (short)f2bf(a2.x + b2.x); v[5] = (short)f2bf(a2.y + b2.y);
  v[6] = (short)f2bf(a2.z + b2.z); v[7] = (short)f2bf(a2.w + b2.w);
  *(short8*)(hbf + (((size_t)row) << 8) + c8) = v;
}

// pos stride-4 (float4-aligned): pos4[n] = {p.x, p.y, p.z, 0}
__global__ void posinit_kernel(const float* __restrict__ positions, float* __restrict__ pos4) {
  int n = blockIdx.x * blockDim.x + threadIdx.x;   // 0..NN-1
  int src = (n & (N_ - 1)) * 3;
  float4 v;
  v.x = positions[src + 0];
  v.y = positions[src + 1];
  v.z = positions[src + 2];
  v.w = 0.f;
  *(float4*)(pos4 + ((size_t)n << 2)) = v;
}

// ---------------- CSR build (counting sort of edges by dst) ----------------

__global__ void deg_kernel(const int* __restrict__ ei, int* __restrict__ deg) {
  int e = blockIdx.x * 256 + threadIdx.x;
  atomicAdd(&deg[ei[E_ + e]], 1);
}

__global__ void scan1_kernel(const int* __restrict__ deg, int* __restrict__ bsum) {
  __shared__ int red[256];
  int t = threadIdx.x;
  red[t] = deg[blockIdx.x * 256 + t];
  __syncthreads();
  for (int off = 128; off > 0; off >>= 1) {
    if (t < off) red[t] += red[t + off];
    __syncthreads();
  }
  if (t == 0) bsum[blockIdx.x] = red[0];
}

__global__ void scan2_kernel(int* __restrict__ bsum) {
  __shared__ int s[256];
  int t = threadIdx.x;
  s[t] = bsum[t];
  __syncthreads();
  for (int off = 1; off < 256; off <<= 1) {
    int v = (t >= off) ? s[t - off] : 0;
    __syncthreads();
    s[t] += v;
    __syncthreads();
  }
  bsum[t] = (t == 0) ? 0 : s[t - 1];
}

// writes BOTH cur and rowptr (no d2d copy)
__global__ void scan3_kernel(const int* __restrict__ deg, const int* __restrict__ bsum,
                             int* __restrict__ cur, int* __restrict__ rowptr) {
  __shared__ int s[256];
  int t = threadIdx.x;
  int i = blockIdx.x * 256 + t;
  s[t] = deg[i];
  __syncthreads();
  for (int off = 1; off < 256; off <<= 1) {
    int v = (t >= off) ? s[t - off] : 0;
    __syncthreads();
    s[t] += v;
    __syncthreads();
  }
  int excl = (t == 0) ? 0 : s[t - 1];
  int v = bsum[blockIdx.x] + excl;
  cur[i] = v;
  rowptr[i] = v;
}

__global__ void scatter_kernel(const int* __restrict__ ei, int* __restrict__ cur,
                               int* __restrict__ src_s) {
  int e = blockIdx.x * 256 + threadIdx.x;
  int s = ei[e], d = ei[E_ + e];
  int p = atomicAdd(&cur[d], 1);
  src_s[p] = s;
}

// ---------------- weight conversion (FRAGMENT-ORDER layout), single kernel ----------------
__global__ void wconv_all(const float* __restrict__ Wm, const float* __restrict__ Wu,
                          unsigned short* __restrict__ Wt1, unsigned short* __restrict__ Wut) {
  int idx = blockIdx.x * 256 + threadIdx.x;    // 0..65535
  int sel = idx >> 14;                          // 0,1: Wm l0,l1 ; 2,3: Wu l0,l1
  int rem = idx & 16383;
  if (sel < 2) {
    const float* W = Wm + (size_t)sel * 513 * H_;
    unsigned short* dst = Wt1 + (size_t)sel * 131072 + ((size_t)rem << 3);
    int g = rem >> 13;
    int r2 = rem & 8191;
    int kc = r2 >> 11, w = (r2 >> 9) & 3, ks = (r2 >> 8) & 1, ni = (r2 >> 6) & 3, lane = r2 & 63;
    int r = lane & 15, q = lane >> 4;
    int n  = (w << 6) + (ni << 4) + r;
    int kb = (g << 8) + (kc << 6) + (ks << 5) + (q << 3);
#pragma unroll
    for (int j = 0; j < 8; ++j)
      dst[j] = f2bf(W[(size_t)(kb + j) * H_ + n]);
  } else {
    const float* W = Wu + (size_t)(sel - 2) * 512 * H_;
    unsigned short* dst = Wut + (size_t)(sel - 2) * 131072 + ((size_t)rem << 3);
    int kc = rem >> 11, w = (rem >> 9) & 3, ks = (rem >> 8) & 1, ni = (rem >> 6) & 3, lane = rem & 63;
    int r = lane & 15, q = lane >> 4;
    int n  = (w << 6) + (ni << 4) + r;
    int kb = (kc << 6) + (ks << 5) + (q << 3);
#pragma unroll
    for (int j = 0; j < 8; ++j)
      dst[j] = f2bf(W[(size_t)(kb + j) * H_ + n]);
  }
}

// ---------------- GEMM1 single-pass (round-10 proven, unchanged) ----------------
__launch_bounds__(256)
__global__ void gemm1_mfma(const unsigned short* __restrict__ hbf,
                           const unsigned short* __restrict__ Wt,
                           const float* __restrict__ bm,
                           unsigned short* __restrict__ X, unsigned short* __restrict__ Zb) {
  __shared__ __align__(16) unsigned short sA[64 * 264];   // 33 KB, full K

  const int t = threadIdx.x;
  const int m0 = blockIdx.x << 6;
  const int w = t >> 6;
  const int lane = t & 63;
  const int q = lane >> 4;
  const int r = lane & 15;
  const int eA = t >> 2;
  const int jA = t & 3;

#pragma unroll
  for (int kc = 0; kc < 4; ++kc) {
    const unsigned short* src = hbf + (((size_t)(m0 + eA)) << 8) + (kc << 6) + (jA << 4);
    unsigned short* dstp = sA + eA * 264 + (kc << 6) + (jA << 4);
    *(short8*)(dstp) = *(const short8*)(src);
    *(short8*)(dstp + 8) = *(const short8*)(src + 8);
  }
  __syncthreads();

  for (int g = 0; g < 2; ++g) {
    f32x4 acc[4][4];
#pragma unroll
    for (int mi = 0; mi < 4; ++mi)
#pragma unroll
      for (int ni = 0; ni < 4; ++ni)
        acc[mi][ni] = (f32x4){0.f, 0.f, 0.f, 0.f};

#pragma unroll
    for (int kc = 0; kc < 4; ++kc) {
#pragma unroll
      for (int ks = 0; ks < 2; ++ks) {
        const int ko = (kc << 6) + (ks << 5) + (q << 3);
        short8 af[4], bfr[4];
#pragma unroll
        for (int mi = 0; mi < 4; ++mi)
          af[mi] = *(const short8*)(sA + (mi * 16 + r) * 264 + ko);
        const size_t wb = ((size_t)((((((g << 2) + kc) << 2) + w) << 1) + ks)) << 11;
#pragma unroll
        for (int ni = 0; ni < 4; ++ni)
          bfr[ni] = *(const short8*)(Wt + wb + (((ni << 6) + lane) << 3));
#pragma unroll
        for (int mi = 0; mi < 4; ++mi)
#pragma unroll
          for (int ni = 0; ni < 4; ++ni)
            acc[mi][ni] = __builtin_amdgcn_mfma_f32_16x16x32_bf16(af[mi], bfr[ni], acc[mi][ni], 0, 0, 0);
      }
    }

#pragma unroll
    for (int ni = 0; ni < 4; ++ni) {
      int n = (w << 6) + ni * 16 + r;
      float bmn = bm[n];
#pragma unroll
      for (int mi = 0; mi < 4; ++mi)
#pragma unroll
        for (int reg = 0; reg < 4; ++reg) {
          size_t idx = (((size_t)(m0 + mi * 16 + q * 4 + reg)) << 8) + n;
          float v = acc[mi][ni][reg];
          if (g == 0) X[idx]  = f2bf(v);
          else        Zb[idx] = f2bf(v + bmn);
        }
    }
  }
}

// ---------------- edge kernel: round-11 inner loop (unroll-2), 2 nodes/wave for more TLP ----------------
__launch_bounds__(256)
__global__ void edge_kernel(const unsigned short* __restrict__ X,
                            const unsigned short* __restrict__ Zb,
                            const float* __restrict__ pos_c,   // stride-4
                            const int* __restrict__ rowptr, const int* __restrict__ src_s,
                            const float* __restrict__ wl, const float* __restrict__ wp,
                            unsigned short* __restrict__ aggb, float* __restrict__ pos_o) {
  const int gid = blockIdx.x * 256 + threadIdx.x;
  const int wave = gid >> 6;
  const int lane = threadIdx.x & 63;

  const float4 wlv = *(const float4*)(wl + (lane << 2));
  const float4 wpv = *(const float4*)(wp + (lane << 2));

#pragma unroll
  for (int ni = 0; ni < 2; ++ni) {
    const int n = (wave << 1) + ni;
    const int e0 = rowptr[n];
    const int e1 = (n == NN_ - 1) ? E_ : rowptr[n + 1];
    const ushort4 zv = *(const ushort4*)(Zb + (((size_t)n) << 8) + (lane << 2));
    const float z0 = bf2f(zv.x), z1 = bf2f(zv.y), z2 = bf2f(zv.z), z3 = bf2f(zv.w);
    const float4 pn = *(const float4*)(pos_c + ((size_t)n << 2));
    float a0 = 0.f, a1 = 0.f, a2 = 0.f, a3 = 0.f;
    float pdx = 0.f, pdy = 0.f, pdz = 0.f;     // per-lane partials (cp unreduced)

    int e = e0;
    for (; e + 2 <= e1; e += 2) {
      const int s0 = src_s[e];
      const int s1 = src_s[e + 1];
      const float4 q0 = *(const float4*)(pos_c + ((size_t)s0 << 2));
      const float4 q1 = *(const float4*)(pos_c + ((size_t)s1 << 2));
      const ushort4 xv0 = *(const ushort4*)(X + (((size_t)s0) << 8) + (lane << 2));
      const ushort4 xv1 = *(const ushort4*)(X + (((size_t)s1) << 8) + (lane << 2));
      // chain 0
      {
        const float dx = pn.x - q0.x, dy = pn.y - q0.y, dz = pn.z - q0.z;
        const float d = sqrtf(dx * dx + dy * dy + dz * dz + 1e-12f);
        const float v0 = fmaxf(bf2f(xv0.x) + z0 + d * wlv.x, 0.f);
        const float v1 = fmaxf(bf2f(xv0.y) + z1 + d * wlv.y, 0.f);
        const float v2 = fmaxf(bf2f(xv0.z) + z2 + d * wlv.z, 0.f);
        const float v3 = fmaxf(bf2f(xv0.w) + z3 + d * wlv.w, 0.f);
        a0 += v0; a1 += v1; a2 += v2; a3 += v3;
        const float cp = v0 * wpv.x + v1 * wpv.y + v2 * wpv.z + v3 * wpv.w;
        pdx += dx * cp; pdy += dy * cp; pdz += dz * cp;
      }
      // chain 1
      {
        const float dx = pn.x - q1.x, dy = pn.y - q1.y, dz = pn.z - q1.z;
        const float d = sqrtf(dx * dx + dy * dy + dz * dz + 1e-12f);
        const float v0 = fmaxf(bf2f(xv1.x) + z0 + d * wlv.x, 0.f);
        const float v1 = fmaxf(bf2f(xv1.y) + z1 + d * wlv.y, 0.f);
        const float v2 = fmaxf(bf2f(xv1.z) + z2 + d * wlv.z, 0.f);
        const float v3 = fmaxf(bf2f(xv1.w) + z3 + d * wlv.w, 0.f);
        a0 += v0; a1 += v1; a2 += v2; a3 += v3;
        const float cp = v0 * wpv.x + v1 * wpv.y + v2 * wpv.z + v3 * wpv.w;
        pdx += dx * cp; pdy += dy * cp; pdz += dz * cp;
      }
    }
    if (e < e1) {
      const int s = src_s[e];
      const float4 q = *(const float4*)(pos_c + ((size_t)s << 2));
      const ushort4 xv = *(const ushort4*)(X + (((size_t)s) << 8) + (lane << 2));
      const float dx = pn.x - q.x, dy = pn.y - q.y, dz = pn.z - q.z;
      const float d = sqrtf(dx * dx + dy * dy + dz * dz + 1e-12f);
      const float v0 = fmaxf(bf2f(xv.x) + z0 + d * wlv.x, 0.f);
      const float v1 = fmaxf(bf2f(xv.y) + z1 + d * wlv.y, 0.f);
      const float v2 = fmaxf(bf2f(xv.z) + z2 + d * wlv.z, 0.f);
      const float v3 = fmaxf(bf2f(xv.w) + z3 + d * wlv.w, 0.f);
      a0 += v0; a1 += v1; a2 += v2; a3 += v3;
      const float cp = v0 * wpv.x + v1 * wpv.y + v2 * wpv.z + v3 * wpv.w;
      pdx += dx * cp; pdy += dy * cp; pdz += dz * cp;
    }

    ushort4 av;
    av.x = f2bf(a0); av.y = f2bf(a1); av.z = f2bf(a2); av.w = f2bf(a3);
    *(ushort4*)(aggb + (((size_t)n) << 8) + (lane << 2)) = av;
#pragma unroll
    for (int m = 1; m < 64; m <<= 1) {
      pdx += __shfl_xor(pdx, m, 64);
      pdy += __shfl_xor(pdy, m, 64);
      pdz += __shfl_xor(pdz, m, 64);
    }
    if (lane == 0) {
      float4 po;
      po.x = pn.x + pdx * 0.25f;
      po.y = pn.y + pdy * 0.25f;
      po.z = pn.z + pdz * 0.25f;
      po.w = 0.f;
      *(float4*)(pos_o + ((size_t)n << 2)) = po;
    }
  }
}

// ---------------- GEMM2 (non-final layers, round-9 proven, unchanged) ----------------
__launch_bounds__(256)
__global__ void upd2_mfma(unsigned short* __restrict__ hbf,
                          const unsigned short* __restrict__ aggb,
                          const unsigned short* __restrict__ Wt,
                          const float* __restrict__ bu) {
  __shared__ __align__(16) unsigned short sA[64 * 72];   // 9 KB

  const int t = threadIdx.x;
  const int m0 = blockIdx.x << 6;
  const int w = t >> 6;
  const int lane = t & 63;
  const int q = lane >> 4;
  const int r = lane & 15;
  const int eA = t >> 2;
  const int jA = t & 3;

  f32x4 acc[4][4];
#pragma unroll
  for (int mi = 0; mi < 4; ++mi)
#pragma unroll
    for (int ni = 0; ni < 4; ++ni)
      acc[mi][ni] = (f32x4){0.f, 0.f, 0.f, 0.f};

  for (int kc = 0; kc < 8; ++kc) {
    __syncthreads();
    {
      const unsigned short* base = (kc < 4) ? hbf : aggb;
      const unsigned short* src = base + (((size_t)(m0 + eA)) << 8) + ((kc & 3) << 6) + (jA << 4);
      unsigned short* dstp = sA + eA * 72 + (jA << 4);
      *(short8*)(dstp) = *(const short8*)(src);
      *(short8*)(dstp + 8) = *(const short8*)(src + 8);
    }
    __syncthreads();
#pragma unroll
    for (int ks = 0; ks < 2; ++ks) {
      const int ko = (ks << 5) + (q << 3);
      short8 af[4], bfr[4];
#pragma unroll
      for (int mi = 0; mi < 4; ++mi)
        af[mi] = *(const short8*)(sA + (mi * 16 + r) * 72 + ko);
      const size_t wb = ((size_t)((((kc << 2) + w) << 1) + ks)) << 11;
#pragma unroll
      for (int ni = 0; ni < 4; ++ni)
        bfr[ni] = *(const short8*)(Wt + wb + (((ni << 6) + lane) << 3));
#pragma unroll
      for (int mi = 0; mi < 4; ++mi)
#pragma unroll
        for (int ni = 0; ni < 4; ++ni)
          acc[mi][ni] = __builtin_amdgcn_mfma_f32_16x16x32_bf16(af[mi], bfr[ni], acc[mi][ni], 0, 0, 0);
    }
  }
  __syncthreads();

#pragma unroll
  for (int ni = 0; ni < 4; ++ni) {
    int n = (w << 6) + ni * 16 + r;
    float buv = bu[n];
#pragma unroll
    for (int mi = 0; mi < 4; ++mi)
#pragma unroll
      for (int reg = 0; reg < 4; ++reg) {
        size_t idx = (((size_t)(m0 + mi * 16 + q * 4 + reg)) << 8) + n;
        float v = bf2f(hbf[idx]) + fmaxf(acc[mi][ni][reg] + buv, 0.f);
        hbf[idx] = f2bf(v);
      }
  }
}

// ---------------- GEMM2 final layer with fused W_out projection (round-10 proven) ----------------
__launch_bounds__(256)
__global__ void upd2_out(const unsigned short* __restrict__ hbf,
                         const unsigned short* __restrict__ aggb,
                         const unsigned short* __restrict__ Wt,
                         const float* __restrict__ bu,
                         const float* __restrict__ Wout, const float* __restrict__ bout,
                         float* __restrict__ out) {
  __shared__ __align__(16) unsigned short sA[64 * 72];   // 9 KB
  __shared__ float sRed[4][64];

  const int t = threadIdx.x;
  const int m0 = blockIdx.x << 6;
  const int w = t >> 6;
  const int lane = t & 63;
  const int q = lane >> 4;
  const int r = lane & 15;
  const int eA = t >> 2;
  const int jA = t & 3;

  f32x4 acc[4][4];
#pragma unroll
  for (int mi = 0; mi < 4; ++mi)
#pragma unroll
    for (int ni = 0; ni < 4; ++ni)
      acc[mi][ni] = (f32x4){0.f, 0.f, 0.f, 0.f};

  for (int kc = 0; kc < 8; ++kc) {
    __syncthreads();
    {
      const unsigned short* base = (kc < 4) ? hbf : aggb;
      const unsigned short* src = base + (((size_t)(m0 + eA)) << 8) + ((kc & 3) << 6) + (jA << 4);
      unsigned short* dstp = sA + eA * 72 + (jA << 4);
      *(short8*)(dstp) = *(const short8*)(src);
      *(short8*)(dstp + 8) = *(const short8*)(src + 8);
    }
    __syncthreads();
#pragma unroll
    for (int ks = 0; ks < 2; ++ks) {
      const int ko = (ks << 5) + (q << 3);
      short8 af[4], bfr[4];
#pragma unroll
      for (int mi = 0; mi < 4; ++mi)
        af[mi] = *(const short8*)(sA + (mi * 16 + r) * 72 + ko);
      const size_t wb = ((size_t)((((kc << 2) + w) << 1) + ks)) << 11;
#pragma unroll
      for (int ni = 0; ni < 4; ++ni)
        bfr[ni] = *(const short8*)(Wt + wb + (((ni << 6) + lane) << 3));
#pragma unroll
      for (int mi = 0; mi < 4; ++mi)
#pragma unroll
        for (int ni = 0; ni < 4; ++ni)
          acc[mi][ni] = __builtin_amdgcn_mfma_f32_16x16x32_bf16(af[mi], bfr[ni], acc[mi][ni], 0, 0, 0);
    }
  }
  __syncthreads();

  float dotp[4][4];
#pragma unroll
  for (int mi = 0; mi < 4; ++mi)
#pragma unroll
    for (int reg = 0; reg < 4; ++reg)
      dotp[mi][reg] = 0.f;

#pragma unroll
  for (int ni = 0; ni < 4; ++ni) {
    int n = (w << 6) + ni * 16 + r;
    float buv = bu[n];
    float won = Wout[n];
#pragma unroll
    for (int mi = 0; mi < 4; ++mi)
#pragma unroll
      for (int reg = 0; reg < 4; ++reg) {
        size_t idx = (((size_t)(m0 + mi * 16 + q * 4 + reg)) << 8) + n;
        float v = bf2f(hbf[idx]) + fmaxf(acc[mi][ni][reg] + buv, 0.f);
        dotp[mi][reg] += v * won;
      }
  }
#pragma unroll
  for (int mask = 1; mask < 16; mask <<= 1)
#pragma unroll
    for (int mi = 0; mi < 4; ++mi)
#pragma unroll
      for (int reg = 0; reg < 4; ++reg)
        dotp[mi][reg] += __shfl_xor(dotp[mi][reg], mask, 64);
  if (r == 0) {
#pragma unroll
    for (int mi = 0; mi < 4; ++mi)
#pragma unroll
      for (int reg = 0; reg < 4; ++reg)
        sRed[w][mi * 16 + q * 4 + reg] = dotp[mi][reg];
  }
  __syncthreads();
  if (t < 64)
    out[m0 + t] = sRed[0][t] + sRed[1][t] + sRed[2][t] + sRed[3][t] + bout[0];
}

// ---------------- launcher ----------------

extern "C" void kernel_launch(void* const* d_in, const int* in_sizes, int n_in,
                              void* d_out, int out_size, void* d_ws, size_t ws_size,
                              hipStream_t stream) {
  const float* x         = (const float*)d_in[0];
  const float* positions = (const float*)d_in[1];
  const float* W_in      = (const float*)d_in[2];
  const float* b_in      = (const float*)d_in[3];
  const float* Wg1       = (const float*)d_in[4];
  const float* bg1       = (const float*)d_in[5];
  const float* Wg2       = (const float*)d_in[6];
  const float* bg2       = (const float*)d_in[7];
  const float* Wm        = (const float*)d_in[8];
  const float* bm        = (const float*)d_in[9];
  const float* Wu        = (const float*)d_in[10];
  const float* bu        = (const float*)d_in[11];
  const float* Wp        = (const float*)d_in[12];
  const float* W_out     = (const float*)d_in[13];
  const float* b_out     = (const float*)d_in[14];
  const int*   ei        = (const int*)d_in[15];
  float* out = (float*)d_out;

  // workspace layout — sequential, non-overlapping (pos stride-4: 1 MB each)
  char* ws = (char*)d_ws;
  unsigned short* hbf   = (unsigned short*)(ws);                 //   0       +32 MB
  unsigned short* X     = (unsigned short*)(ws +  33554432UL);   //  32 MB    +32 MB
  unsigned short* Zb    = (unsigned short*)(ws +  67108864UL);   //  64 MB    +32 MB
  unsigned short* aggb  = (unsigned short*)(ws + 100663296UL);   //  96 MB    +32 MB
  float*          posA  = (float*)(ws + 134217728UL);            // +1 MB (stride-4)
  float*          posB  = (float*)(ws + 135266304UL);            // +1 MB (stride-4)
  float*          g     = (float*)(ws + 136314880UL);            // +2 MB
  float*          h0    = (float*)(ws + 138412032UL);            // +32 KB
  unsigned short* Wt1   = (unsigned short*)(ws + 138444800UL);   // +512 KB (2 layers, frag-order)
  unsigned short* Wut   = (unsigned short*)(ws + 138969088UL);   // +512 KB (2 layers, frag-order)
  int*            deg   = (int*)(ws + 139493376UL);              // +256 KB
  int*            cur   = (int*)(ws + 139755520UL);              // +256 KB
  int*            bsum  = (int*)(ws + 140017664UL);              // +1 KB
  int*            rowptr= (int*)(ws + 140018688UL);              // +256 KB -> ends 140280832
  int*            src_s = (int*)(ws + 140280832UL);              // +1 MB   -> ends 141329408

  // ---- CSR (counting sort by dst) ----
  hipMemsetAsync(deg, 0, (size_t)NN_ * sizeof(int), stream);
  deg_kernel<<<E_ / 256, 256, 0, stream>>>(ei, deg);
  scan1_kernel<<<256, 256, 0, stream>>>(deg, bsum);
  scan2_kernel<<<1, 256, 0, stream>>>(bsum);
  scan3_kernel<<<256, 256, 0, stream>>>(deg, bsum, cur, rowptr);
  scatter_kernel<<<E_ / 256, 256, 0, stream>>>(ei, cur, src_s);

  // ---- weight conversion (frag-order, one kernel) ----
  wconv_all<<<256, 256, 0, stream>>>(Wm, Wu, Wt1, Wut);

  // ---- node/pos init ----
  h0_kernel<<<B_, 256, 0, stream>>>(x, W_in, b_in, h0);
  meand_g_kernel<<<N_, 256, 0, stream>>>(positions, Wg1, bg1, Wg2, bg2, g);
  hbfinit_kernel<<<NN_ * 32 / 256, 256, 0, stream>>>(h0, g, hbf);
  posinit_kernel<<<NN_ / 256, 256, 0, stream>>>(positions, posA);

  float* pos_cur = posA;
  float* pos_nxt = posB;
  for (int l = 0; l < L_; ++l) {
    gemm1_mfma<<<NN_ / 64, 256, 0, stream>>>(hbf, Wt1 + (size_t)l * 131072,
                                             bm + (size_t)l * H_, X, Zb);
    edge_kernel<<<NN_ / 8, 256, 0, stream>>>(X, Zb, pos_cur, rowptr, src_s,
                                             Wm + (size_t)l * 513 * H_ + 512 * H_,
                                             Wp + (size_t)l * H_, aggb, pos_nxt);
    if (l < L_ - 1) {
      upd2_mfma<<<NN_ / 64, 256, 0, stream>>>(hbf, aggb, Wut + (size_t)l * 131072,
                                              bu + (size_t)l * H_);
    } else {
      upd2_out<<<NN_ / 64, 256, 0, stream>>>(hbf, aggb, Wut + (size_t)l * 131072,
                                             bu + (size_t)l * H_, W_out, b_out, out);
    }
    float* tmp = pos_cur; pos_cur = pos_nxt; pos_nxt = tmp;
  }
}

// Round 14
// 374.651 us; speedup vs baseline: 1.0863x; 1.0059x over previous
//
#include <hip/hip_runtime.h>
#include <math.h>

#define B_ 32
#define F_ 128
#define H_ 256
#define N_ 2048
#define L_ 2
#define E_ 262144
#define NN_ 65536          // B_*N_
// DEG = E/(B*N) = 4

typedef __attribute__((ext_vector_type(8))) short short8;   // 8 bf16 = 4 VGPRs (MFMA A/B frag)
typedef __attribute__((ext_vector_type(4))) float f32x4;    // MFMA C/D frag

static __device__ __forceinline__ unsigned short f2bf(float f) {
  unsigned int u = __float_as_uint(f);
  u += 0x7FFF + ((u >> 16) & 1);      // round-to-nearest-even
  return (unsigned short)(u >> 16);
}
static __device__ __forceinline__ float bf2f(unsigned short u) {
  return __uint_as_float(((unsigned int)u) << 16);
}

// ---------------- small kernels ----------------

__global__ void h0_kernel(const float* __restrict__ x, const float* __restrict__ W_in,
                          const float* __restrict__ b_in, float* __restrict__ h0) {
  int b = blockIdx.x;
  int j = threadIdx.x;
  float acc = b_in[j];
#pragma unroll 8
  for (int k = 0; k < F_; ++k)
    acc += x[b * F_ + k] * W_in[k * H_ + j];
  h0[b * H_ + j] = acc;
}

// fused mean-distance + geometric MLP: one block per node n
__global__ void meand_g_kernel(const float* __restrict__ positions,
                               const float* __restrict__ Wg1, const float* __restrict__ bg1,
                               const float* __restrict__ Wg2, const float* __restrict__ bg2,
                               float* __restrict__ g) {
  __shared__ float red[256];
  __shared__ float hid[128];
  int n = blockIdx.x;
  int t = threadIdx.x;
  float px = positions[n * 3 + 0], py = positions[n * 3 + 1], pz = positions[n * 3 + 2];
  float s = 0.f;
  for (int j = t; j < N_; j += 256) {
    float dx = px - positions[j * 3 + 0];
    float dy = py - positions[j * 3 + 1];
    float dz = pz - positions[j * 3 + 2];
    s += sqrtf(dx * dx + dy * dy + dz * dz);
  }
  red[t] = s;
  __syncthreads();
  for (int off = 128; off > 0; off >>= 1) {
    if (t < off) red[t] += red[t + off];
    __syncthreads();
  }
  float md = red[0] / (float)(N_ - 1);
  if (t < 128) {
    float w = Wg1[t] + Wg1[128 + t] + Wg1[256 + t];
    hid[t] = fmaxf(md * w + bg1[t], 0.f);
  }
  __syncthreads();
  float acc = bg2[t];
#pragma unroll 8
  for (int k = 0; k < 128; ++k)
    acc += hid[k] * Wg2[k * H_ + t];
  g[n * H_ + t] = acc;
}

// hbf[b*N+n][:] = bf16(h0[b][:] + g[n][:])  — bf16-only node state
__global__ void hbfinit_kernel(const float* __restrict__ h0, const float* __restrict__ g,
                               unsigned short* __restrict__ hbf) {
  int idx = blockIdx.x * blockDim.x + threadIdx.x;  // NN*32, 8 ch each
  int row = idx >> 5;
  int c8 = (idx & 31) << 3;
  const float* hp = h0 + (row >> 11) * H_ + c8;
  const float* gp = g + (row & (N_ - 1)) * H_ + c8;
  const float4 a = *(const float4*)hp;
  const float4 a2 = *(const float4*)(hp + 4);
  const float4 b = *(const float4*)gp;
  const float4 b2 = *(const float4*)(gp + 4);
  short8 v;
  v[0] = (short)f2bf(a.x + b.x);  v[1] = (short)f2bf(a.y + b.y);
  v[2] = (short)f2bf(a.z + b.z);  v[3] = (short)f2bf(a.w + b.w);
  v[4] = (short)f2bf(a2.x + b2.x); v[5] = (short)f2bf(a2.y + b2.y);
  v[6] = (short)f2bf(a2.z + b2.z); v[7] = (short)f2bf(a2.w + b2.w);
  *(short8*)(hbf + (((size_t)row) << 8) + c8) = v;
}

// pos stride-4 (float4-aligned): pos4[n] = {p.x, p.y, p.z, 0}
__global__ void posinit_kernel(const float* __restrict__ positions, float* __restrict__ pos4) {
  int n = blockIdx.x * blockDim.x + threadIdx.x;   // 0..NN-1
  int src = (n & (N_ - 1)) * 3;
  float4 v;
  v.x = positions[src + 0];
  v.y = positions[src + 1];
  v.z = positions[src + 2];
  v.w = 0.f;
  *(float4*)(pos4 + ((size_t)n << 2)) = v;
}

// ---------------- CSR build (counting sort of edges by dst) ----------------

__global__ void deg_kernel(const int* __restrict__ ei, int* __restrict__ deg) {
  int e = blockIdx.x * 256 + threadIdx.x;
  atomicAdd(&deg[ei[E_ + e]], 1);
}

__global__ void scan1_kernel(const int* __restrict__ deg, int* __restrict__ bsum) {
  __shared__ int red[256];
  int t = threadIdx.x;
  red[t] = deg[blockIdx.x * 256 + t];
  __syncthreads();
  for (int off = 128; off > 0; off >>= 1) {
    if (t < off) red[t] += red[t + off];
    __syncthreads();
  }
  if (t == 0) bsum[blockIdx.x] = red[0];
}

__global__ void scan2_kernel(int* __restrict__ bsum) {
  __shared__ int s[256];
  int t = threadIdx.x;
  s[t] = bsum[t];
  __syncthreads();
  for (int off = 1; off < 256; off <<= 1) {
    int v = (t >= off) ? s[t - off] : 0;
    __syncthreads();
    s[t] += v;
    __syncthreads();
  }
  bsum[t] = (t == 0) ? 0 : s[t - 1];
}

// writes BOTH cur and rowptr (no d2d copy)
__global__ void scan3_kernel(const int* __restrict__ deg, const int* __restrict__ bsum,
                             int* __restrict__ cur, int* __restrict__ rowptr) {
  __shared__ int s[256];
  int t = threadIdx.x;
  int i = blockIdx.x * 256 + t;
  s[t] = deg[i];
  __syncthreads();
  for (int off = 1; off < 256; off <<= 1) {
    int v = (t >= off) ? s[t - off] : 0;
    __syncthreads();
    s[t] += v;
    __syncthreads();
  }
  int excl = (t == 0) ? 0 : s[t - 1];
  int v = bsum[blockIdx.x] + excl;
  cur[i] = v;
  rowptr[i] = v;
}

__global__ void scatter_kernel(const int* __restrict__ ei, int* __restrict__ cur,
                               int* __restrict__ src_s) {
  int e = blockIdx.x * 256 + threadIdx.x;
  int s = ei[e], d = ei[E_ + e];
  int p = atomicAdd(&cur[d], 1);
  src_s[p] = s;
}

// ---------------- weight conversion (FRAGMENT-ORDER layout), single kernel ----------------
__global__ void wconv_all(const float* __restrict__ Wm, const float* __restrict__ Wu,
                          unsigned short* __restrict__ Wt1, unsigned short* __restrict__ Wut) {
  int idx = blockIdx.x * 256 + threadIdx.x;    // 0..65535
  int sel = idx >> 14;                          // 0,1: Wm l0,l1 ; 2,3: Wu l0,l1
  int rem = idx & 16383;
  if (sel < 2) {
    const float* W = Wm + (size_t)sel * 513 * H_;
    unsigned short* dst = Wt1 + (size_t)sel * 131072 + ((size_t)rem << 3);
    int g = rem >> 13;
    int r2 = rem & 8191;
    int kc = r2 >> 11, w = (r2 >> 9) & 3, ks = (r2 >> 8) & 1, ni = (r2 >> 6) & 3, lane = r2 & 63;
    int r = lane & 15, q = lane >> 4;
    int n  = (w << 6) + (ni << 4) + r;
    int kb = (g << 8) + (kc << 6) + (ks << 5) + (q << 3);
#pragma unroll
    for (int j = 0; j < 8; ++j)
      dst[j] = f2bf(W[(size_t)(kb + j) * H_ + n]);
  } else {
    const float* W = Wu + (size_t)(sel - 2) * 512 * H_;
    unsigned short* dst = Wut + (size_t)(sel - 2) * 131072 + ((size_t)rem << 3);
    int kc = rem >> 11, w = (rem >> 9) & 3, ks = (rem >> 8) & 1, ni = (rem >> 6) & 3, lane = rem & 63;
    int r = lane & 15, q = lane >> 4;
    int n  = (w << 6) + (ni << 4) + r;
    int kb = (kc << 6) + (ks << 5) + (q << 3);
#pragma unroll
    for (int j = 0; j < 8; ++j)
      dst[j] = f2bf(W[(size_t)(kb + j) * H_ + n]);
  }
}

// ---------------- GEMM1 single-pass (round-10 proven, unchanged) ----------------
__launch_bounds__(256)
__global__ void gemm1_mfma(const unsigned short* __restrict__ hbf,
                           const unsigned short* __restrict__ Wt,
                           const float* __restrict__ bm,
                           unsigned short* __restrict__ X, unsigned short* __restrict__ Zb) {
  __shared__ __align__(16) unsigned short sA[64 * 264];   // 33 KB, full K

  const int t = threadIdx.x;
  const int m0 = blockIdx.x << 6;
  const int w = t >> 6;
  const int lane = t & 63;
  const int q = lane >> 4;
  const int r = lane & 15;
  const int eA = t >> 2;
  const int jA = t & 3;

#pragma unroll
  for (int kc = 0; kc < 4; ++kc) {
    const unsigned short* src = hbf + (((size_t)(m0 + eA)) << 8) + (kc << 6) + (jA << 4);
    unsigned short* dstp = sA + eA * 264 + (kc << 6) + (jA << 4);
    *(short8*)(dstp) = *(const short8*)(src);
    *(short8*)(dstp + 8) = *(const short8*)(src + 8);
  }
  __syncthreads();

  for (int g = 0; g < 2; ++g) {
    f32x4 acc[4][4];
#pragma unroll
    for (int mi = 0; mi < 4; ++mi)
#pragma unroll
      for (int ni = 0; ni < 4; ++ni)
        acc[mi][ni] = (f32x4){0.f, 0.f, 0.f, 0.f};

#pragma unroll
    for (int kc = 0; kc < 4; ++kc) {
#pragma unroll
      for (int ks = 0; ks < 2; ++ks) {
        const int ko = (kc << 6) + (ks << 5) + (q << 3);
        short8 af[4], bfr[4];
#pragma unroll
        for (int mi = 0; mi < 4; ++mi)
          af[mi] = *(const short8*)(sA + (mi * 16 + r) * 264 + ko);
        const size_t wb = ((size_t)((((((g << 2) + kc) << 2) + w) << 1) + ks)) << 11;
#pragma unroll
        for (int ni = 0; ni < 4; ++ni)
          bfr[ni] = *(const short8*)(Wt + wb + (((ni << 6) + lane) << 3));
#pragma unroll
        for (int mi = 0; mi < 4; ++mi)
#pragma unroll
          for (int ni = 0; ni < 4; ++ni)
            acc[mi][ni] = __builtin_amdgcn_mfma_f32_16x16x32_bf16(af[mi], bfr[ni], acc[mi][ni], 0, 0, 0);
      }
    }

#pragma unroll
    for (int ni = 0; ni < 4; ++ni) {
      int n = (w << 6) + ni * 16 + r;
      float bmn = bm[n];
#pragma unroll
      for (int mi = 0; mi < 4; ++mi)
#pragma unroll
        for (int reg = 0; reg < 4; ++reg) {
          size_t idx = (((size_t)(m0 + mi * 16 + q * 4 + reg)) << 8) + n;
          float v = acc[mi][ni][reg];
          if (g == 0) X[idx]  = f2bf(v);
          else        Zb[idx] = f2bf(v + bmn);
        }
    }
  }
}

// ---------------- edge kernel: round-11 inner loop (unroll-2), 1 node/wave (max TLP) ----------------
__launch_bounds__(256)
__global__ void edge_kernel(const unsigned short* __restrict__ X,
                            const unsigned short* __restrict__ Zb,
                            const float* __restrict__ pos_c,   // stride-4
                            const int* __restrict__ rowptr, const int* __restrict__ src_s,
                            const float* __restrict__ wl, const float* __restrict__ wp,
                            unsigned short* __restrict__ aggb, float* __restrict__ pos_o) {
  const int gid = blockIdx.x * 256 + threadIdx.x;
  const int n = gid >> 6;                 // one node per wave
  const int lane = threadIdx.x & 63;

  const float4 wlv = *(const float4*)(wl + (lane << 2));
  const float4 wpv = *(const float4*)(wp + (lane << 2));

  const int e0 = rowptr[n];
  const int e1 = (n == NN_ - 1) ? E_ : rowptr[n + 1];
  const ushort4 zv = *(const ushort4*)(Zb + (((size_t)n) << 8) + (lane << 2));
  const float z0 = bf2f(zv.x), z1 = bf2f(zv.y), z2 = bf2f(zv.z), z3 = bf2f(zv.w);
  const float4 pn = *(const float4*)(pos_c + ((size_t)n << 2));
  float a0 = 0.f, a1 = 0.f, a2 = 0.f, a3 = 0.f;
  float pdx = 0.f, pdy = 0.f, pdz = 0.f;     // per-lane partials (cp unreduced)

  int e = e0;
  for (; e + 2 <= e1; e += 2) {
    const int s0 = src_s[e];
    const int s1 = src_s[e + 1];
    const float4 q0 = *(const float4*)(pos_c + ((size_t)s0 << 2));
    const float4 q1 = *(const float4*)(pos_c + ((size_t)s1 << 2));
    const ushort4 xv0 = *(const ushort4*)(X + (((size_t)s0) << 8) + (lane << 2));
    const ushort4 xv1 = *(const ushort4*)(X + (((size_t)s1) << 8) + (lane << 2));
    // chain 0
    {
      const float dx = pn.x - q0.x, dy = pn.y - q0.y, dz = pn.z - q0.z;
      const float d = sqrtf(dx * dx + dy * dy + dz * dz + 1e-12f);
      const float v0 = fmaxf(bf2f(xv0.x) + z0 + d * wlv.x, 0.f);
      const float v1 = fmaxf(bf2f(xv0.y) + z1 + d * wlv.y, 0.f);
      const float v2 = fmaxf(bf2f(xv0.z) + z2 + d * wlv.z, 0.f);
      const float v3 = fmaxf(bf2f(xv0.w) + z3 + d * wlv.w, 0.f);
      a0 += v0; a1 += v1; a2 += v2; a3 += v3;
      const float cp = v0 * wpv.x + v1 * wpv.y + v2 * wpv.z + v3 * wpv.w;
      pdx += dx * cp; pdy += dy * cp; pdz += dz * cp;
    }
    // chain 1
    {
      const float dx = pn.x - q1.x, dy = pn.y - q1.y, dz = pn.z - q1.z;
      const float d = sqrtf(dx * dx + dy * dy + dz * dz + 1e-12f);
      const float v0 = fmaxf(bf2f(xv1.x) + z0 + d * wlv.x, 0.f);
      const float v1 = fmaxf(bf2f(xv1.y) + z1 + d * wlv.y, 0.f);
      const float v2 = fmaxf(bf2f(xv1.z) + z2 + d * wlv.z, 0.f);
      const float v3 = fmaxf(bf2f(xv1.w) + z3 + d * wlv.w, 0.f);
      a0 += v0; a1 += v1; a2 += v2; a3 += v3;
      const float cp = v0 * wpv.x + v1 * wpv.y + v2 * wpv.z + v3 * wpv.w;
      pdx += dx * cp; pdy += dy * cp; pdz += dz * cp;
    }
  }
  if (e < e1) {
    const int s = src_s[e];
    const float4 q = *(const float4*)(pos_c + ((size_t)s << 2));
    const ushort4 xv = *(const ushort4*)(X + (((size_t)s) << 8) + (lane << 2));
    const float dx = pn.x - q.x, dy = pn.y - q.y, dz = pn.z - q.z;
    const float d = sqrtf(dx * dx + dy * dy + dz * dz + 1e-12f);
    const float v0 = fmaxf(bf2f(xv.x) + z0 + d * wlv.x, 0.f);
    const float v1 = fmaxf(bf2f(xv.y) + z1 + d * wlv.y, 0.f);
    const float v2 = fmaxf(bf2f(xv.z) + z2 + d * wlv.z, 0.f);
    const float v3 = fmaxf(bf2f(xv.w) + z3 + d * wlv.w, 0.f);
    a0 += v0; a1 += v1; a2 += v2; a3 += v3;
    const float cp = v0 * wpv.x + v1 * wpv.y + v2 * wpv.z + v3 * wpv.w;
    pdx += dx * cp; pdy += dy * cp; pdz += dz * cp;
  }

  ushort4 av;
  av.x = f2bf(a0); av.y = f2bf(a1); av.z = f2bf(a2); av.w = f2bf(a3);
  *(ushort4*)(aggb + (((size_t)n) << 8) + (lane << 2)) = av;
#pragma unroll
  for (int m = 1; m < 64; m <<= 1) {
    pdx += __shfl_xor(pdx, m, 64);
    pdy += __shfl_xor(pdy, m, 64);
    pdz += __shfl_xor(pdz, m, 64);
  }
  if (lane == 0) {
    float4 po;
    po.x = pn.x + pdx * 0.25f;
    po.y = pn.y + pdy * 0.25f;
    po.z = pn.z + pdz * 0.25f;
    po.w = 0.f;
    *(float4*)(pos_o + ((size_t)n << 2)) = po;
  }
}

// ---------------- GEMM2 (non-final layers, round-9 proven, unchanged) ----------------
__launch_bounds__(256)
__global__ void upd2_mfma(unsigned short* __restrict__ hbf,
                          const unsigned short* __restrict__ aggb,
                          const unsigned short* __restrict__ Wt,
                          const float* __restrict__ bu) {
  __shared__ __align__(16) unsigned short sA[64 * 72];   // 9 KB

  const int t = threadIdx.x;
  const int m0 = blockIdx.x << 6;
  const int w = t >> 6;
  const int lane = t & 63;
  const int q = lane >> 4;
  const int r = lane & 15;
  const int eA = t >> 2;
  const int jA = t & 3;

  f32x4 acc[4][4];
#pragma unroll
  for (int mi = 0; mi < 4; ++mi)
#pragma unroll
    for (int ni = 0; ni < 4; ++ni)
      acc[mi][ni] = (f32x4){0.f, 0.f, 0.f, 0.f};

  for (int kc = 0; kc < 8; ++kc) {
    __syncthreads();
    {
      const unsigned short* base = (kc < 4) ? hbf : aggb;
      const unsigned short* src = base + (((size_t)(m0 + eA)) << 8) + ((kc & 3) << 6) + (jA << 4);
      unsigned short* dstp = sA + eA * 72 + (jA << 4);
      *(short8*)(dstp) = *(const short8*)(src);
      *(short8*)(dstp + 8) = *(const short8*)(src + 8);
    }
    __syncthreads();
#pragma unroll
    for (int ks = 0; ks < 2; ++ks) {
      const int ko = (ks << 5) + (q << 3);
      short8 af[4], bfr[4];
#pragma unroll
      for (int mi = 0; mi < 4; ++mi)
        af[mi] = *(const short8*)(sA + (mi * 16 + r) * 72 + ko);
      const size_t wb = ((size_t)((((kc << 2) + w) << 1) + ks)) << 11;
#pragma unroll
      for (int ni = 0; ni < 4; ++ni)
        bfr[ni] = *(const short8*)(Wt + wb + (((ni << 6) + lane) << 3));
#pragma unroll
      for (int mi = 0; mi < 4; ++mi)
#pragma unroll
        for (int ni = 0; ni < 4; ++ni)
          acc[mi][ni] = __builtin_amdgcn_mfma_f32_16x16x32_bf16(af[mi], bfr[ni], acc[mi][ni], 0, 0, 0);
    }
  }
  __syncthreads();

#pragma unroll
  for (int ni = 0; ni < 4; ++ni) {
    int n = (w << 6) + ni * 16 + r;
    float buv = bu[n];
#pragma unroll
    for (int mi = 0; mi < 4; ++mi)
#pragma unroll
      for (int reg = 0; reg < 4; ++reg) {
        size_t idx = (((size_t)(m0 + mi * 16 + q * 4 + reg)) << 8) + n;
        float v = bf2f(hbf[idx]) + fmaxf(acc[mi][ni][reg] + buv, 0.f);
        hbf[idx] = f2bf(v);
      }
  }
}

// ---------------- GEMM2 final layer with fused W_out projection (round-10 proven) ----------------
__launch_bounds__(256)
__global__ void upd2_out(const unsigned short* __restrict__ hbf,
                         const unsigned short* __restrict__ aggb,
                         const unsigned short* __restrict__ Wt,
                         const float* __restrict__ bu,
                         const float* __restrict__ Wout, const float* __restrict__ bout,
                         float* __restrict__ out) {
  __shared__ __align__(16) unsigned short sA[64 * 72];   // 9 KB
  __shared__ float sRed[4][64];

  const int t = threadIdx.x;
  const int m0 = blockIdx.x << 6;
  const int w = t >> 6;
  const int lane = t & 63;
  const int q = lane >> 4;
  const int r = lane & 15;
  const int eA = t >> 2;
  const int jA = t & 3;

  f32x4 acc[4][4];
#pragma unroll
  for (int mi = 0; mi < 4; ++mi)
#pragma unroll
    for (int ni = 0; ni < 4; ++ni)
      acc[mi][ni] = (f32x4){0.f, 0.f, 0.f, 0.f};

  for (int kc = 0; kc < 8; ++kc) {
    __syncthreads();
    {
      const unsigned short* base = (kc < 4) ? hbf : aggb;
      const unsigned short* src = base + (((size_t)(m0 + eA)) << 8) + ((kc & 3) << 6) + (jA << 4);
      unsigned short* dstp = sA + eA * 72 + (jA << 4);
      *(short8*)(dstp) = *(const short8*)(src);
      *(short8*)(dstp + 8) = *(const short8*)(src + 8);
    }
    __syncthreads();
#pragma unroll
    for (int ks = 0; ks < 2; ++ks) {
      const int ko = (ks << 5) + (q << 3);
      short8 af[4], bfr[4];
#pragma unroll
      for (int mi = 0; mi < 4; ++mi)
        af[mi] = *(const short8*)(sA + (mi * 16 + r) * 72 + ko);
      const size_t wb = ((size_t)((((kc << 2) + w) << 1) + ks)) << 11;
#pragma unroll
      for (int ni = 0; ni < 4; ++ni)
        bfr[ni] = *(const short8*)(Wt + wb + (((ni << 6) + lane) << 3));
#pragma unroll
      for (int mi = 0; mi < 4; ++mi)
#pragma unroll
        for (int ni = 0; ni < 4; ++ni)
          acc[mi][ni] = __builtin_amdgcn_mfma_f32_16x16x32_bf16(af[mi], bfr[ni], acc[mi][ni], 0, 0, 0);
    }
  }
  __syncthreads();

  float dotp[4][4];
#pragma unroll
  for (int mi = 0; mi < 4; ++mi)
#pragma unroll
    for (int reg = 0; reg < 4; ++reg)
      dotp[mi][reg] = 0.f;

#pragma unroll
  for (int ni = 0; ni < 4; ++ni) {
    int n = (w << 6) + ni * 16 + r;
    float buv = bu[n];
    float won = Wout[n];
#pragma unroll
    for (int mi = 0; mi < 4; ++mi)
#pragma unroll
      for (int reg = 0; reg < 4; ++reg) {
        size_t idx = (((size_t)(m0 + mi * 16 + q * 4 + reg)) << 8) + n;
        float v = bf2f(hbf[idx]) + fmaxf(acc[mi][ni][reg] + buv, 0.f);
        dotp[mi][reg] += v * won;
      }
  }
#pragma unroll
  for (int mask = 1; mask < 16; mask <<= 1)
#pragma unroll
    for (int mi = 0; mi < 4; ++mi)
#pragma unroll
      for (int reg = 0; reg < 4; ++reg)
        dotp[mi][reg] += __shfl_xor(dotp[mi][reg], mask, 64);
  if (r == 0) {
#pragma unroll
    for (int mi = 0; mi < 4; ++mi)
#pragma unroll
      for (int reg = 0; reg < 4; ++reg)
        sRed[w][mi * 16 + q * 4 + reg] = dotp[mi][reg];
  }
  __syncthreads();
  if (t < 64)
    out[m0 + t] = sRed[0][t] + sRed[1][t] + sRed[2][t] + sRed[3][t] + bout[0];
}

// ---------------- launcher ----------------

extern "C" void kernel_launch(void* const* d_in, const int* in_sizes, int n_in,
                              void* d_out, int out_size, void* d_ws, size_t ws_size,
                              hipStream_t stream) {
  const float* x         = (const float*)d_in[0];
  const float* positions = (const float*)d_in[1];
  const float* W_in      = (const float*)d_in[2];
  const float* b_in      = (const float*)d_in[3];
  const float* Wg1       = (const float*)d_in[4];
  const float* bg1       = (const float*)d_in[5];
  const float* Wg2       = (const float*)d_in[6];
  const float* bg2       = (const float*)d_in[7];
  const float* Wm        = (const float*)d_in[8];
  const float* bm        = (const float*)d_in[9];
  const float* Wu        = (const float*)d_in[10];
  const float* bu        = (const float*)d_in[11];
  const float* Wp        = (const float*)d_in[12];
  const float* W_out     = (const float*)d_in[13];
  const float* b_out     = (const float*)d_in[14];
  const int*   ei        = (const int*)d_in[15];
  float* out = (float*)d_out;

  // workspace layout — sequential, non-overlapping (pos stride-4: 1 MB each)
  char* ws = (char*)d_ws;
  unsigned short* hbf   = (unsigned short*)(ws);                 //   0       +32 MB
  unsigned short* X     = (unsigned short*)(ws +  33554432UL);   //  32 MB    +32 MB
  unsigned short* Zb    = (unsigned short*)(ws +  67108864UL);   //  64 MB    +32 MB
  unsigned short* aggb  = (unsigned short*)(ws + 100663296UL);   //  96 MB    +32 MB
  float*          posA  = (float*)(ws + 134217728UL);            // +1 MB (stride-4)
  float*          posB  = (float*)(ws + 135266304UL);            // +1 MB (stride-4)
  float*          g     = (float*)(ws + 136314880UL);            // +2 MB
  float*          h0    = (float*)(ws + 138412032UL);            // +32 KB
  unsigned short* Wt1   = (unsigned short*)(ws + 138444800UL);   // +512 KB (2 layers, frag-order)
  unsigned short* Wut   = (unsigned short*)(ws + 138969088UL);   // +512 KB (2 layers, frag-order)
  int*            deg   = (int*)(ws + 139493376UL);              // +256 KB
  int*            cur   = (int*)(ws + 139755520UL);              // +256 KB
  int*            bsum  = (int*)(ws + 140017664UL);              // +1 KB
  int*            rowptr= (int*)(ws + 140018688UL);              // +256 KB -> ends 140280832
  int*            src_s = (int*)(ws + 140280832UL);              // +1 MB   -> ends 141329408

  // ---- CSR (counting sort by dst) ----
  hipMemsetAsync(deg, 0, (size_t)NN_ * sizeof(int), stream);
  deg_kernel<<<E_ / 256, 256, 0, stream>>>(ei, deg);
  scan1_kernel<<<256, 256, 0, stream>>>(deg, bsum);
  scan2_kernel<<<1, 256, 0, stream>>>(bsum);
  scan3_kernel<<<256, 256, 0, stream>>>(deg, bsum, cur, rowptr);
  scatter_kernel<<<E_ / 256, 256, 0, stream>>>(ei, cur, src_s);

  // ---- weight conversion (frag-order, one kernel) ----
  wconv_all<<<256, 256, 0, stream>>>(Wm, Wu, Wt1, Wut);

  // ---- node/pos init ----
  h0_kernel<<<B_, 256, 0, stream>>>(x, W_in, b_in, h0);
  meand_g_kernel<<<N_, 256, 0, stream>>>(positions, Wg1, bg1, Wg2, bg2, g);
  hbfinit_kernel<<<NN_ * 32 / 256, 256, 0, stream>>>(h0, g, hbf);
  posinit_kernel<<<NN_ / 256, 256, 0, stream>>>(positions, posA);

  float* pos_cur = posA;
  float* pos_nxt = posB;
  for (int l = 0; l < L_; ++l) {
    gemm1_mfma<<<NN_ / 64, 256, 0, stream>>>(hbf, Wt1 + (size_t)l * 131072,
                                             bm + (size_t)l * H_, X, Zb);
    edge_kernel<<<NN_ / 4, 256, 0, stream>>>(X, Zb, pos_cur, rowptr, src_s,
                                             Wm + (size_t)l * 513 * H_ + 512 * H_,
                                             Wp + (size_t)l * H_, aggb, pos_nxt);
    if (l < L_ - 1) {
      upd2_mfma<<<NN_ / 64, 256, 0, stream>>>(hbf, aggb, Wut + (size_t)l * 131072,
                                              bu + (size_t)l * H_);
    } else {
      upd2_out<<<NN_ / 64, 256, 0, stream>>>(hbf, aggb, Wut + (size_t)l * 131072,
                                             bu + (size_t)l * H_, W_out, b_out, out);
    }
    float* tmp = pos_cur; pos_cur = pos_nxt; pos_nxt = tmp;
  }
}